// Round 12
// baseline (197.546 us; speedup 1.0000x reference)
//
#include <hip/hip_runtime.h>
#include <hip/hip_bf16.h>
#include <math.h>

#define N_TOK 2048
#define C_DIM 512
#define H_NUM 8
#define DH 64
#define M_LM 64
#define SEG 32
#define KL 4
#define SCALE 0.125f

typedef __attribute__((ext_vector_type(8))) short short8;
typedef __attribute__((ext_vector_type(8))) unsigned short ushort8v;
typedef __attribute__((ext_vector_type(4))) float f32x4;

__device__ inline unsigned short f2bf(float f) {
  unsigned u = __float_as_uint(f);
  u += 0x7FFF + ((u >> 16) & 1);
  return (unsigned short)(u >> 16);
}
__device__ inline float bf2f(unsigned short h) {
  return __uint_as_float(((unsigned)h) << 16);
}

// LDS swizzle for the MFMA GEMM (R7-proven): k-octet stride 1024B is 0 mod 32
// banks; XOR row bits with ko, same on write and read => layout-only.
__device__ inline int swz(int ko, int row) {
  return ((ko * 64 + row) * 8) ^ (ko << 3);
}

// gemm_qk staging rotation (R10-proven: conflicts 3.15M -> 0). Colliding
// lanes share kk&7 and differ in kk>>3; rotate WITHIN the 16B chunk:
// col' = (col&~3) | ((col + (kk>>3)) & 3). Read un-rotates with the
// compile-time constant (kk2>>3)&3 — pure register renaming, values
// bit-identical.
__device__ inline int qrot(int k, int c) {
  return (c & ~3) | ((c + (k >> 3)) & 3);
}

// ---------------------------------------------------------------------------
// Q/K fp32 GEMM — 128x64 tile, 8x4 outputs/thread, BK=32 (this round's single
// change). Per-output chain UNCHANGED: acc(n,d) += A[n][k]*B[d][k], k=0..511
// strictly ascending, one fp32 accumulator => bit-identical Q/K/route (tile
// shape only reassigns outputs to threads — R8 proved this passes).
// Why: R10 analysis — per CU 8192 ds_read_b128 x 12cyc = 41 us LDS-pipe
// floor; measured 48 = 85% of pipe. Kernel is LDS-INSTRUCTION-bound; only
// lever is fewer LDS reads per FMA. 8x4/thread: 3 reads per 32 FMAs (was
// 2 per 16) -> 6144 instrs/CU -> ~31 us floor. Grid 256 = 1 block/CU: VGPR
// no longer caps anything (grid-pinned occupancy), dodging the R5/R11 trap.
// History (do not retry): R5 dbuf, R6 global_load_lds, R8 32x64 tile,
// R9 chunk-XOR, R11 BK=64 — all neutral or regressed.
// ---------------------------------------------------------------------------
__global__ __launch_bounds__(256) void gemm_qk(
    const float* __restrict__ A, const float* __restrict__ B,
    float* __restrict__ out_q, float* __restrict__ out_k,
    unsigned short* __restrict__ kbf)
{
  __shared__ float As[32][132];  // [k][m], 128 rows + pad
  __shared__ float Bs[32][68];   // [k][j], 64 cols + pad
  int tid = threadIdx.x;
  int tx = tid & 15, ty = tid >> 4;    // tx: col quad (64 cols), ty: row octet (128 rows)
  int row0 = blockIdx.y << 7;
  int col0 = blockIdx.x << 6;
  float acc[8][4] = {};
  int kk = tid & 31, rr = tid >> 5;    // staging: 32 k-cols x 8 row-groups

  float pa[16], pb[8];
#pragma unroll
  for (int i = 0; i < 16; i++)
    pa[i] = A[(size_t)(row0 + rr + i * 8) * 512 + kk];
#pragma unroll
  for (int i = 0; i < 8; i++)
    pb[i] = B[(size_t)(col0 + rr + i * 8) * 512 + kk];

  for (int k0 = 0; k0 < 512; k0 += 32) {
    __syncthreads();
#pragma unroll
    for (int i = 0; i < 16; i++) As[kk][qrot(kk, rr + i * 8)] = pa[i];
#pragma unroll
    for (int i = 0; i < 8; i++)  Bs[kk][qrot(kk, rr + i * 8)] = pb[i];
    __syncthreads();
    if (k0 + 32 < 512) {
#pragma unroll
      for (int i = 0; i < 16; i++)
        pa[i] = A[(size_t)(row0 + rr + i * 8) * 512 + k0 + 32 + kk];
#pragma unroll
      for (int i = 0; i < 8; i++)
        pb[i] = B[(size_t)(col0 + rr + i * 8) * 512 + k0 + 32 + kk];
    }
#pragma unroll
    for (int kk2 = 0; kk2 < 32; kk2++) {
      const int a2 = kk2 >> 3;
      float ar0[4], ar1[4], br[4];
      *(float4*)ar0 = *(const float4*)&As[kk2][ty << 3];
      *(float4*)ar1 = *(const float4*)&As[kk2][(ty << 3) + 4];
      *(float4*)br  = *(const float4*)&Bs[kk2][tx << 2];
      float a[8], b[4];
#pragma unroll
      for (int j = 0; j < 4; j++) {
        a[j]     = ar0[(j + a2) & 3];
        a[j + 4] = ar1[(j + a2) & 3];
        b[j]     = br[(j + a2) & 3];
      }
#pragma unroll
      for (int i = 0; i < 8; i++)
#pragma unroll
        for (int j = 0; j < 4; j++) acc[i][j] += a[i] * b[j];
    }
  }

  int role = col0 >> 9;
  int h = (col0 >> 6) & 7;
  float* dst = (role == 0) ? out_q : out_k;
#pragma unroll
  for (int i = 0; i < 8; i++) {
    int n = row0 + (ty << 3) + i;
#pragma unroll
    for (int j = 0; j < 4; j++) {
      int d = (tx << 2) + j;
      float v = acc[i][j];
      dst[(size_t)((h << 11) + n) * DH + d] = v;
      if (role == 1) kbf[(size_t)((h << 11) + n) * DH + d] = f2bf(v);
    }
  }
}

// ---------------------------------------------------------------------------
// Fused 2-term bf16 splits for x (rows 2048), w_qkv V-rows (512), w_proj (512).
// (R2 version, byte-identical.)
// ---------------------------------------------------------------------------
__global__ void split3_kernel(const float* __restrict__ x, const float* __restrict__ wv,
                              const float* __restrict__ wp,
                              unsigned short* __restrict__ X2,
                              unsigned short* __restrict__ W2v,
                              unsigned short* __restrict__ WP2)
{
  int idx = blockIdx.x * 256 + threadIdx.x;   // 0 .. 1572863
  const float* src; unsigned short* dst; int li;
  if (idx < 1048576)      { src = x;  dst = X2;  li = idx; }
  else if (idx < 1310720) { src = wv; dst = W2v; li = idx - 1048576; }
  else                    { src = wp; dst = WP2; li = idx - 1310720; }
  int r = li >> 9, k = li & 511;
  float a = src[li];
  unsigned short h1 = f2bf(a);
  float r1 = a - bf2f(h1);
  dst[(size_t)(r << 10) + k] = h1;
  dst[(size_t)(r << 10) + 512 + k] = f2bf(r1);
}

// ---------------------------------------------------------------------------
// bf16-split MFMA GEMM, 3 products + LDS XOR swizzle (R7-proven).
// mode 0: V-scatter as SINGLE bf16 -> ov16[(h<<11)+row][d]
// mode 1: ofull = acc + bias (fp32).
// ---------------------------------------------------------------------------
__global__ __launch_bounds__(256) void gemm_mfma(
    const unsigned short* __restrict__ A2, const unsigned short* __restrict__ B2,
    unsigned short* __restrict__ ov16, float* __restrict__ ofull,
    const float* __restrict__ bias, int ldout, int mode)
{
  __shared__ short Al[4096];
  __shared__ short Bl[4096];
  int tid = threadIdx.x;
  int lane = tid & 63, w = tid >> 6;
  int row0 = blockIdx.y << 6, col0 = blockIdx.x << 6;
  int wr = (w >> 1) * 32, wc = (w & 1) * 32;
  int m_lo = tid & 7, h8 = (tid >> 3) & 7, m_hi = tid >> 6;
  int ms = m_hi * 8 + m_lo;  // 0..31
  int q = lane >> 4, ln = lane & 15;

  f32x4 acc[2][2];
#pragma unroll
  for (int mi = 0; mi < 2; mi++)
#pragma unroll
    for (int ni = 0; ni < 2; ni++)
#pragma unroll
      for (int r = 0; r < 4; r++) acc[mi][ni][r] = 0.0f;

  for (int s = 0; s < 24; s++) {
    int ka = (s < 8) ? s * 64 : (s < 16) ? 512 + (s - 8) * 64 : (s - 16) * 64;
    int kb = (s < 8) ? s * 64 : (s < 16) ? (s - 8) * 64 : 512 + (s - 16) * 64;
    short8 a0 = *(const short8*)(A2 + (size_t)(row0 + ms) * 1024 + ka + h8 * 8);
    short8 a1 = *(const short8*)(A2 + (size_t)(row0 + ms + 32) * 1024 + ka + h8 * 8);
    short8 b0 = *(const short8*)(B2 + (size_t)(col0 + ms) * 1024 + kb + h8 * 8);
    short8 b1 = *(const short8*)(B2 + (size_t)(col0 + ms + 32) * 1024 + kb + h8 * 8);
    __syncthreads();
    *(short8*)&Al[swz(h8, ms)] = a0;
    *(short8*)&Al[swz(h8, ms + 32)] = a1;
    *(short8*)&Bl[swz(h8, ms)] = b0;
    *(short8*)&Bl[swz(h8, ms + 32)] = b1;
    __syncthreads();
    short8 af[2][2], bf[2][2];
#pragma unroll
    for (int sub = 0; sub < 2; sub++)
#pragma unroll
      for (int i = 0; i < 2; i++) {
        af[sub][i] = *(const short8*)&Al[swz(sub * 4 + q, wr + i * 16 + ln)];
        bf[sub][i] = *(const short8*)&Bl[swz(sub * 4 + q, wc + i * 16 + ln)];
      }
#pragma unroll
    for (int sub = 0; sub < 2; sub++)
#pragma unroll
      for (int mi = 0; mi < 2; mi++)
#pragma unroll
        for (int ni = 0; ni < 2; ni++)
          acc[mi][ni] = __builtin_amdgcn_mfma_f32_16x16x32_bf16(
              af[sub][mi], bf[sub][ni], acc[mi][ni], 0, 0, 0);
  }

  if (mode == 0) {
    int hh = (col0 >> 6) & 7;
#pragma unroll
    for (int mi = 0; mi < 2; mi++)
#pragma unroll
      for (int ni = 0; ni < 2; ni++)
#pragma unroll
        for (int r = 0; r < 4; r++) {
          int row = row0 + wr + mi * 16 + q * 4 + r;
          int d = wc + ni * 16 + ln;
          ov16[(size_t)((hh << 11) + row) * DH + d] = f2bf(acc[mi][ni][r]);
        }
  } else {
#pragma unroll
    for (int mi = 0; mi < 2; mi++)
#pragma unroll
      for (int ni = 0; ni < 2; ni++)
#pragma unroll
        for (int r = 0; r < 4; r++) {
          int row = row0 + wr + mi * 16 + q * 4 + r;
          int col = col0 + wc + ni * 16 + ln;
          ofull[(size_t)row * ldout + col] = acc[mi][ni][r] + bias[col];
        }
  }
}

// ---------------------------------------------------------------------------
// Centroids: cent[h][m][d] = mean_s k[h][m*32+s][d]  (R2 version)
// ---------------------------------------------------------------------------
__global__ void centroid_kernel(const float* __restrict__ kb, float* __restrict__ cent)
{
  int idx = blockIdx.x * blockDim.x + threadIdx.x;  // 32768
  int m = (idx >> 6) & 63;
  int h = idx >> 12;
  int d = idx & 63;
  const float* base = kb + ((size_t)(h << 11) + m * SEG) * DH + d;
  float s = 0.f;
#pragma unroll
  for (int ss = 0; ss < SEG; ss++) s += base[(size_t)ss * DH];
  cent[idx] = s * (1.0f / SEG);
}

// ---------------------------------------------------------------------------
// Route + top-4 (R2 version, frozen).
// ---------------------------------------------------------------------------
__global__ __launch_bounds__(256) void route_topk_kernel(
    const float* __restrict__ qb, const float* __restrict__ cent, int* __restrict__ topk)
{
  __shared__ float centT[64][65];
  __shared__ float qs[4][64];
  int tid = threadIdx.x;
  int wave = tid >> 6, lane = tid & 63;
  int qi = (blockIdx.x << 2) + wave;
  int h = qi >> 11;  // uniform across block
  qs[wave][lane] = qb[(size_t)qi * DH + lane];
  const float4* c4 = (const float4*)(cent + ((size_t)h << 12));
#pragma unroll
  for (int i = 0; i < 4; i++) {
    int f4 = tid + 256 * i;       // 0..1023
    int m = f4 >> 4;
    int d0 = (f4 & 15) * 4;
    float4 v = c4[f4];
    centT[d0][m] = v.x; centT[d0 + 1][m] = v.y;
    centT[d0 + 2][m] = v.z; centT[d0 + 3][m] = v.w;
  }
  __syncthreads();
  float dot = 0.f;
#pragma unroll
  for (int d = 0; d < 64; d++) dot += qs[wave][d] * centT[d][lane];
  float val = dot * SCALE;
  for (int r = 0; r < KL; r++) {
    float v = val;
    int id = lane;
#pragma unroll
    for (int off = 32; off; off >>= 1) {
      float ov = __shfl_xor(v, off, 64);
      int oi = __shfl_xor(id, off, 64);
      if (ov > v || (ov == v && oi < id)) { v = ov; id = oi; }
    }
    if (lane == 0) topk[qi * KL + r] = id;
    if (lane == id) val = -INFINITY;
  }
}

// ---------------------------------------------------------------------------
// Sparse attention with bf16 K/V gather (R2 passing version, byte-identical).
// ---------------------------------------------------------------------------
__global__ __launch_bounds__(256) void attn_kernel(
    const float* __restrict__ qb, const unsigned short* __restrict__ kbf,
    const unsigned short* __restrict__ vbf, const int* __restrict__ topk,
    unsigned short* __restrict__ ao2)
{
  __shared__ float probs[4][132];   // [wave][si*33 + ss]
  int tid = threadIdx.x;
  int wave = tid >> 6, lane = tid & 63;
  int qi = (blockIdx.x << 2) + wave;
  int h = qi >> 11, n = qi & 2047;
  int4 tk = *(const int4*)(topk + qi * KL);
  int segArr[4] = {tk.x, tk.y, tk.z, tk.w};
  const float* qrow = qb + (size_t)qi * DH;
  float4 qreg[4];
#pragma unroll
  for (int j = 0; j < 2; j++) {
    qreg[j * 2]     = *(const float4*)(qrow + ((lane & 3) + 4 * j) * 8);
    qreg[j * 2 + 1] = *(const float4*)(qrow + ((lane & 3) + 4 * j) * 8 + 4);
  }

  float e[8];
  float score[8];
#pragma unroll
  for (int g = 0; g < 8; g++) {
    int seg = segArr[g >> 1];
    int key_n = seg * SEG + (lane >> 2) + 16 * (g & 1);
    const unsigned short* krow = kbf + ((size_t)(h << 11) + key_n) * DH;
    float a0 = 0.f, a1 = 0.f, a2 = 0.f, a3 = 0.f;
#pragma unroll
    for (int j = 0; j < 2; j++) {
      ushort8v kv = *(const ushort8v*)(krow + ((lane & 3) + 4 * j) * 8);
      float4 q0 = qreg[j * 2], q1 = qreg[j * 2 + 1];
      a0 += q0.x * bf2f(kv[0]); a1 += q0.y * bf2f(kv[1]);
      a2 += q0.z * bf2f(kv[2]); a3 += q0.w * bf2f(kv[3]);
      a0 += q1.x * bf2f(kv[4]); a1 += q1.y * bf2f(kv[5]);
      a2 += q1.z * bf2f(kv[6]); a3 += q1.w * bf2f(kv[7]);
    }
    float acc = (a0 + a1) + (a2 + a3);
    acc += __shfl_xor(acc, 1, 64);
    acc += __shfl_xor(acc, 2, 64);
    score[g] = acc * SCALE;
  }
  float mx = score[0];
#pragma unroll
  for (int g = 1; g < 8; g++) mx = fmaxf(mx, score[g]);
#pragma unroll
  for (int off = 4; off < 64; off <<= 1) mx = fmaxf(mx, __shfl_xor(mx, off, 64));
  float ls = 0.f;
#pragma unroll
  for (int g = 0; g < 8; g++) { e[g] = expf(score[g] - mx); ls += e[g]; }
#pragma unroll
  for (int off = 4; off < 64; off <<= 1) ls += __shfl_xor(ls, off, 64);
  float inv = 1.0f / ls;
  if ((lane & 3) == 0) {
#pragma unroll
    for (int g = 0; g < 8; g++)
      probs[wave][(g >> 1) * 33 + (lane >> 2) + 16 * (g & 1)] = e[g] * inv;
  }
  __syncthreads();

  // PV
  int gi = lane >> 4, lx = lane & 15;
  int rh = lx >> 3, dl = lx & 7;
  int seg = segArr[gi];
  const unsigned short* vbase = vbf + ((size_t)(h << 11) + seg * SEG) * DH + dl * 8;
  float o[8] = {};
#pragma unroll
  for (int ss = 0; ss < 16; ss++) {
    int row = rh * 16 + ss;
    float p = probs[wave][gi * 33 + row];
    ushort8v vv = *(const ushort8v*)(vbase + (size_t)row * DH);
#pragma unroll
    for (int j = 0; j < 8; j++) o[j] += p * bf2f(vv[j]);
  }
#pragma unroll
  for (int off = 8; off < 64; off <<= 1) {
#pragma unroll
    for (int j = 0; j < 8; j++) o[j] += __shfl_xor(o[j], off, 64);
  }
  if (lane < 8) {
    ushort8v hi8, lo8;
#pragma unroll
    for (int j = 0; j < 8; j++) {
      unsigned short hb = f2bf(o[j]);
      hi8[j] = (short)hb;
      lo8[j] = (short)f2bf(o[j] - bf2f(hb));
    }
    *(ushort8v*)(ao2 + (size_t)n * 1024 + (h << 6) + (lane << 3)) = hi8;
    *(ushort8v*)(ao2 + (size_t)n * 1024 + 512 + (h << 6) + (lane << 3)) = lo8;
  }
}

// ---------------------------------------------------------------------------
extern "C" void kernel_launch(void* const* d_in, const int* in_sizes, int n_in,
                              void* d_out, int out_size, void* d_ws, size_t ws_size,
                              hipStream_t stream)
{
  const float* x      = (const float*)d_in[0];   // (1,2048,512)
  const float* w_qkv  = (const float*)d_in[1];   // (1536,512)
  const float* w_proj = (const float*)d_in[2];   // (512,512)
  const float* b_proj = (const float*)d_in[3];   // (512,)
  float* out = (float*)d_out;                    // (1,2048,512)

  float* base = (float*)d_ws;
  float* qbuf = base;                                        // 1,048,576 f
  float* kbuf = base + 1048576;                              // 1,048,576 f
  unsigned short* vbf = (unsigned short*)(base + 2097152);   // 8x2048x64 bf16
  unsigned short* kbf = (unsigned short*)(base + 2621440);   // 8x2048x64 bf16
  float* cent = base + 3145728;                              // 32,768 f
  int*   topk = (int*)(base + 3178496);                      // 65,536 i
  unsigned short* X2  = (unsigned short*)(base + 3244032);   // 2048x1024 bf16 (2-term)
  unsigned short* W2v = (unsigned short*)(base + 4292608);   // 512x1024  (V rows of w_qkv)
  unsigned short* WP2 = (unsigned short*)(base + 4554752);   // 512x1024  (w_proj)
  unsigned short* AO2 = X2;  // overlay: X2 dead after V GEMM

  // 1. fused 2-term bf16 splits (x, V-rows of w_qkv, w_proj)
  split3_kernel<<<6144, 256, 0, stream>>>(x, w_qkv + 1024 * 512, w_proj,
                                          X2, W2v, WP2);
  // 2. Q/K fp32 GEMM (128x64 tile, 8x4/thread, chain frozen) + bf16 K epilogue
  {
    dim3 grid(1024 / 64, N_TOK / 128);   // 16 x 16 = 256 blocks
    gemm_qk<<<grid, 256, 0, stream>>>(x, w_qkv, qbuf, kbuf, kbf);
  }
  // 3. V via bf16-split MFMA (swizzled LDS) -> single-bf16 vbf
  {
    dim3 grid(512 / 64, N_TOK / 64);
    gemm_mfma<<<grid, 256, 0, stream>>>(X2, W2v, vbf, nullptr, nullptr, 0, 0);
  }
  // 4. centroids (from bit-exact fp32 k)
  centroid_kernel<<<(H_NUM * M_LM * DH) / 256, 256, 0, stream>>>(kbuf, cent);
  // 5. route + top-4 (bit-exact scores)
  route_topk_kernel<<<(H_NUM * N_TOK) / 4, 256, 0, stream>>>(qbuf, cent, topk);
  // 6. sparse attention (bf16 gather) -> 2-term AO2 (overlays X2)
  attn_kernel<<<(H_NUM * N_TOK) / 4, 256, 0, stream>>>(qbuf, kbf, vbf, topk, AO2);
  // 7. proj GEMM (MFMA swizzled, 3 products) + bias
  {
    dim3 grid(C_DIM / 64, N_TOK / 64);
    gemm_mfma<<<grid, 256, 0, stream>>>(AO2, WP2, nullptr, out, b_proj, C_DIM, 1);
  }
}

// Round 13
// 189.429 us; speedup vs baseline: 1.0428x; 1.0428x over previous
//
#include <hip/hip_runtime.h>
#include <hip/hip_bf16.h>
#include <math.h>

#define N_TOK 2048
#define C_DIM 512
#define H_NUM 8
#define DH 64
#define M_LM 64
#define SEG 32
#define KL 4
#define SCALE 0.125f

typedef __attribute__((ext_vector_type(8))) short short8;
typedef __attribute__((ext_vector_type(8))) unsigned short ushort8v;
typedef __attribute__((ext_vector_type(4))) float f32x4;

__device__ inline unsigned short f2bf(float f) {
  unsigned u = __float_as_uint(f);
  u += 0x7FFF + ((u >> 16) & 1);
  return (unsigned short)(u >> 16);
}
__device__ inline float bf2f(unsigned short h) {
  return __uint_as_float(((unsigned)h) << 16);
}

// LDS swizzle for the MFMA GEMM (R7-proven): k-octet stride 1024B is 0 mod 32
// banks; XOR row bits with ko, same on write and read => layout-only.
__device__ inline int swz(int ko, int row) {
  return ((ko * 64 + row) * 8) ^ (ko << 3);
}

// gemm_qk staging rotation (R10-proven: conflicts 3.15M -> 0). Colliding
// lanes share kk&7 and differ in kk>>3; rotate WITHIN the 16B chunk:
// col' = (col&~3) | ((col + (kk>>3)) & 3). Read un-rotates with the
// compile-time constant (kk2>>3)&3 — pure register renaming, values
// bit-identical.
__device__ inline int qrot(int k, int c) {
  return (c & ~3) | ((c + (k >> 3)) & 3);
}

// ---------------------------------------------------------------------------
// Q/K fp32 GEMM — exact R10 body (64x64, BK=32, rotation, conflicts 0,
// 48 us: CLOSED after R5/R6/R8/R9/R11/R12 all neutral-or-regressed).
// This round's single change: centroid fused into the K-role epilogue,
// BIT-EXACTLY — a K block covers rows [row0,row0+64) of head h = centroids
// m = row0/32, row0/32+1. Stage fp32 K-values into the dead As/Bs tiles;
// 128 threads sum 32 values each in the SAME ascending-n order as the old
// centroid_kernel (same fp32 values, same order => same bits => frozen
// route untouched). kbuf (fp32 K) lost its only consumer -> store dropped
// (-4MB write, -4MB read).
// ---------------------------------------------------------------------------
__global__ __launch_bounds__(256) void gemm_qk(
    const float* __restrict__ A, const float* __restrict__ B,
    float* __restrict__ out_q, unsigned short* __restrict__ kbf,
    float* __restrict__ cent)
{
  __shared__ float As[32][68];   // [k][m], pad->16B-aligned rows
  __shared__ float Bs[32][68];   // [k][j]
  int tid = threadIdx.x;
  int tx = tid & 15, ty = tid >> 4;
  int row0 = blockIdx.y << 6;
  int col0 = blockIdx.x << 6;
  float acc[4][4] = {};
  int kk = tid & 31, rr = tid >> 5;   // staging: 32 k-cols x 8 row-groups

  float pa[8], pb[8];
#pragma unroll
  for (int i = 0; i < 8; i++) {
    pa[i] = A[(size_t)(row0 + rr + i * 8) * 512 + kk];
    pb[i] = B[(size_t)(col0 + rr + i * 8) * 512 + kk];
  }

  for (int k0 = 0; k0 < 512; k0 += 32) {
    __syncthreads();
#pragma unroll
    for (int i = 0; i < 8; i++) {
      As[kk][qrot(kk, rr + i * 8)] = pa[i];
      Bs[kk][qrot(kk, rr + i * 8)] = pb[i];
    }
    __syncthreads();
    if (k0 + 32 < 512) {
#pragma unroll
      for (int i = 0; i < 8; i++) {
        pa[i] = A[(size_t)(row0 + rr + i * 8) * 512 + k0 + 32 + kk];
        pb[i] = B[(size_t)(col0 + rr + i * 8) * 512 + k0 + 32 + kk];
      }
    }
#pragma unroll
    for (int kk2 = 0; kk2 < 32; kk2++) {
      const int a2 = kk2 >> 3;
      float ar[4], br[4];
      *(float4*)ar = *(const float4*)&As[kk2][ty << 2];
      *(float4*)br = *(const float4*)&Bs[kk2][tx << 2];
      float a[4], b[4];
#pragma unroll
      for (int j = 0; j < 4; j++) {
        a[j] = ar[(j + a2) & 3];
        b[j] = br[(j + a2) & 3];
      }
#pragma unroll
      for (int i = 0; i < 4; i++)
#pragma unroll
        for (int j = 0; j < 4; j++) acc[i][j] += a[i] * b[j];
    }
  }

  int role = col0 >> 9;
  int h = (col0 >> 6) & 7;
  if (role == 0) {
#pragma unroll
    for (int i = 0; i < 4; i++) {
      int n = row0 + (ty << 2) + i;
#pragma unroll
      for (int j = 0; j < 4; j++) {
        int d = (tx << 2) + j;
        out_q[(size_t)((h << 11) + n) * DH + d] = acc[i][j];
      }
    }
  } else {
    // bf16 K store + exact-order fused centroid (reuses dead As/Bs).
    __syncthreads();   // all lanes done reading As/Bs from the main loop
#pragma unroll
    for (int i = 0; i < 4; i++) {
      int nl = (ty << 2) + i;          // local row 0..63
#pragma unroll
      for (int j = 0; j < 4; j++) {
        int d = (tx << 2) + j;
        float v = acc[i][j];
        kbf[(size_t)((h << 11) + row0 + nl) * DH + d] = f2bf(v);
        if (nl < 32) As[nl][d] = v; else Bs[nl - 32][d] = v;
      }
    }
    __syncthreads();
    if (tid < 128) {
      int m_loc = tid >> 6, d = tid & 63;
      float s = 0.f;
      if (m_loc == 0) {
#pragma unroll
        for (int ss = 0; ss < SEG; ss++) s += As[ss][d];   // ascending n
      } else {
#pragma unroll
        for (int ss = 0; ss < SEG; ss++) s += Bs[ss][d];   // ascending n
      }
      int m = (row0 >> 5) + m_loc;
      cent[(h << 12) + (m << 6) + d] = s * (1.0f / SEG);
    }
  }
}

// ---------------------------------------------------------------------------
// Fused 2-term bf16 splits for x (rows 2048), w_qkv V-rows (512), w_proj (512).
// (R2 version, byte-identical.)
// ---------------------------------------------------------------------------
__global__ void split3_kernel(const float* __restrict__ x, const float* __restrict__ wv,
                              const float* __restrict__ wp,
                              unsigned short* __restrict__ X2,
                              unsigned short* __restrict__ W2v,
                              unsigned short* __restrict__ WP2)
{
  int idx = blockIdx.x * 256 + threadIdx.x;   // 0 .. 1572863
  const float* src; unsigned short* dst; int li;
  if (idx < 1048576)      { src = x;  dst = X2;  li = idx; }
  else if (idx < 1310720) { src = wv; dst = W2v; li = idx - 1048576; }
  else                    { src = wp; dst = WP2; li = idx - 1310720; }
  int r = li >> 9, k = li & 511;
  float a = src[li];
  unsigned short h1 = f2bf(a);
  float r1 = a - bf2f(h1);
  dst[(size_t)(r << 10) + k] = h1;
  dst[(size_t)(r << 10) + 512 + k] = f2bf(r1);
}

// ---------------------------------------------------------------------------
// bf16-split MFMA GEMM, 3 products + LDS XOR swizzle (R7-proven).
// mode 0: V-scatter as SINGLE bf16 -> ov16[(h<<11)+row][d]
// mode 1: ofull = acc + bias (fp32).
// ---------------------------------------------------------------------------
__global__ __launch_bounds__(256) void gemm_mfma(
    const unsigned short* __restrict__ A2, const unsigned short* __restrict__ B2,
    unsigned short* __restrict__ ov16, float* __restrict__ ofull,
    const float* __restrict__ bias, int ldout, int mode)
{
  __shared__ short Al[4096];
  __shared__ short Bl[4096];
  int tid = threadIdx.x;
  int lane = tid & 63, w = tid >> 6;
  int row0 = blockIdx.y << 6, col0 = blockIdx.x << 6;
  int wr = (w >> 1) * 32, wc = (w & 1) * 32;
  int m_lo = tid & 7, h8 = (tid >> 3) & 7, m_hi = tid >> 6;
  int ms = m_hi * 8 + m_lo;  // 0..31
  int q = lane >> 4, ln = lane & 15;

  f32x4 acc[2][2];
#pragma unroll
  for (int mi = 0; mi < 2; mi++)
#pragma unroll
    for (int ni = 0; ni < 2; ni++)
#pragma unroll
      for (int r = 0; r < 4; r++) acc[mi][ni][r] = 0.0f;

  for (int s = 0; s < 24; s++) {
    int ka = (s < 8) ? s * 64 : (s < 16) ? 512 + (s - 8) * 64 : (s - 16) * 64;
    int kb = (s < 8) ? s * 64 : (s < 16) ? (s - 8) * 64 : 512 + (s - 16) * 64;
    short8 a0 = *(const short8*)(A2 + (size_t)(row0 + ms) * 1024 + ka + h8 * 8);
    short8 a1 = *(const short8*)(A2 + (size_t)(row0 + ms + 32) * 1024 + ka + h8 * 8);
    short8 b0 = *(const short8*)(B2 + (size_t)(col0 + ms) * 1024 + kb + h8 * 8);
    short8 b1 = *(const short8*)(B2 + (size_t)(col0 + ms + 32) * 1024 + kb + h8 * 8);
    __syncthreads();
    *(short8*)&Al[swz(h8, ms)] = a0;
    *(short8*)&Al[swz(h8, ms + 32)] = a1;
    *(short8*)&Bl[swz(h8, ms)] = b0;
    *(short8*)&Bl[swz(h8, ms + 32)] = b1;
    __syncthreads();
    short8 af[2][2], bf[2][2];
#pragma unroll
    for (int sub = 0; sub < 2; sub++)
#pragma unroll
      for (int i = 0; i < 2; i++) {
        af[sub][i] = *(const short8*)&Al[swz(sub * 4 + q, wr + i * 16 + ln)];
        bf[sub][i] = *(const short8*)&Bl[swz(sub * 4 + q, wc + i * 16 + ln)];
      }
#pragma unroll
    for (int sub = 0; sub < 2; sub++)
#pragma unroll
      for (int mi = 0; mi < 2; mi++)
#pragma unroll
        for (int ni = 0; ni < 2; ni++)
          acc[mi][ni] = __builtin_amdgcn_mfma_f32_16x16x32_bf16(
              af[sub][mi], bf[sub][ni], acc[mi][ni], 0, 0, 0);
  }

  if (mode == 0) {
    int hh = (col0 >> 6) & 7;
#pragma unroll
    for (int mi = 0; mi < 2; mi++)
#pragma unroll
      for (int ni = 0; ni < 2; ni++)
#pragma unroll
        for (int r = 0; r < 4; r++) {
          int row = row0 + wr + mi * 16 + q * 4 + r;
          int d = wc + ni * 16 + ln;
          ov16[(size_t)((hh << 11) + row) * DH + d] = f2bf(acc[mi][ni][r]);
        }
  } else {
#pragma unroll
    for (int mi = 0; mi < 2; mi++)
#pragma unroll
      for (int ni = 0; ni < 2; ni++)
#pragma unroll
        for (int r = 0; r < 4; r++) {
          int row = row0 + wr + mi * 16 + q * 4 + r;
          int col = col0 + wc + ni * 16 + ln;
          ofull[(size_t)row * ldout + col] = acc[mi][ni][r] + bias[col];
        }
  }
}

// ---------------------------------------------------------------------------
// Route + top-4 (R2 version, frozen).
// ---------------------------------------------------------------------------
__global__ __launch_bounds__(256) void route_topk_kernel(
    const float* __restrict__ qb, const float* __restrict__ cent, int* __restrict__ topk)
{
  __shared__ float centT[64][65];
  __shared__ float qs[4][64];
  int tid = threadIdx.x;
  int wave = tid >> 6, lane = tid & 63;
  int qi = (blockIdx.x << 2) + wave;
  int h = qi >> 11;  // uniform across block
  qs[wave][lane] = qb[(size_t)qi * DH + lane];
  const float4* c4 = (const float4*)(cent + ((size_t)h << 12));
#pragma unroll
  for (int i = 0; i < 4; i++) {
    int f4 = tid + 256 * i;       // 0..1023
    int m = f4 >> 4;
    int d0 = (f4 & 15) * 4;
    float4 v = c4[f4];
    centT[d0][m] = v.x; centT[d0 + 1][m] = v.y;
    centT[d0 + 2][m] = v.z; centT[d0 + 3][m] = v.w;
  }
  __syncthreads();
  float dot = 0.f;
#pragma unroll
  for (int d = 0; d < 64; d++) dot += qs[wave][d] * centT[d][lane];
  float val = dot * SCALE;
  for (int r = 0; r < KL; r++) {
    float v = val;
    int id = lane;
#pragma unroll
    for (int off = 32; off; off >>= 1) {
      float ov = __shfl_xor(v, off, 64);
      int oi = __shfl_xor(id, off, 64);
      if (ov > v || (ov == v && oi < id)) { v = ov; id = oi; }
    }
    if (lane == 0) topk[qi * KL + r] = id;
    if (lane == id) val = -INFINITY;
  }
}

// ---------------------------------------------------------------------------
// Sparse attention with bf16 K/V gather (R2 passing version, byte-identical).
// ---------------------------------------------------------------------------
__global__ __launch_bounds__(256) void attn_kernel(
    const float* __restrict__ qb, const unsigned short* __restrict__ kbf,
    const unsigned short* __restrict__ vbf, const int* __restrict__ topk,
    unsigned short* __restrict__ ao2)
{
  __shared__ float probs[4][132];   // [wave][si*33 + ss]
  int tid = threadIdx.x;
  int wave = tid >> 6, lane = tid & 63;
  int qi = (blockIdx.x << 2) + wave;
  int h = qi >> 11, n = qi & 2047;
  int4 tk = *(const int4*)(topk + qi * KL);
  int segArr[4] = {tk.x, tk.y, tk.z, tk.w};
  const float* qrow = qb + (size_t)qi * DH;
  float4 qreg[4];
#pragma unroll
  for (int j = 0; j < 2; j++) {
    qreg[j * 2]     = *(const float4*)(qrow + ((lane & 3) + 4 * j) * 8);
    qreg[j * 2 + 1] = *(const float4*)(qrow + ((lane & 3) + 4 * j) * 8 + 4);
  }

  float e[8];
  float score[8];
#pragma unroll
  for (int g = 0; g < 8; g++) {
    int seg = segArr[g >> 1];
    int key_n = seg * SEG + (lane >> 2) + 16 * (g & 1);
    const unsigned short* krow = kbf + ((size_t)(h << 11) + key_n) * DH;
    float a0 = 0.f, a1 = 0.f, a2 = 0.f, a3 = 0.f;
#pragma unroll
    for (int j = 0; j < 2; j++) {
      ushort8v kv = *(const ushort8v*)(krow + ((lane & 3) + 4 * j) * 8);
      float4 q0 = qreg[j * 2], q1 = qreg[j * 2 + 1];
      a0 += q0.x * bf2f(kv[0]); a1 += q0.y * bf2f(kv[1]);
      a2 += q0.z * bf2f(kv[2]); a3 += q0.w * bf2f(kv[3]);
      a0 += q1.x * bf2f(kv[4]); a1 += q1.y * bf2f(kv[5]);
      a2 += q1.z * bf2f(kv[6]); a3 += q1.w * bf2f(kv[7]);
    }
    float acc = (a0 + a1) + (a2 + a3);
    acc += __shfl_xor(acc, 1, 64);
    acc += __shfl_xor(acc, 2, 64);
    score[g] = acc * SCALE;
  }
  float mx = score[0];
#pragma unroll
  for (int g = 1; g < 8; g++) mx = fmaxf(mx, score[g]);
#pragma unroll
  for (int off = 4; off < 64; off <<= 1) mx = fmaxf(mx, __shfl_xor(mx, off, 64));
  float ls = 0.f;
#pragma unroll
  for (int g = 0; g < 8; g++) { e[g] = expf(score[g] - mx); ls += e[g]; }
#pragma unroll
  for (int off = 4; off < 64; off <<= 1) ls += __shfl_xor(ls, off, 64);
  float inv = 1.0f / ls;
  if ((lane & 3) == 0) {
#pragma unroll
    for (int g = 0; g < 8; g++)
      probs[wave][(g >> 1) * 33 + (lane >> 2) + 16 * (g & 1)] = e[g] * inv;
  }
  __syncthreads();

  // PV
  int gi = lane >> 4, lx = lane & 15;
  int rh = lx >> 3, dl = lx & 7;
  int seg = segArr[gi];
  const unsigned short* vbase = vbf + ((size_t)(h << 11) + seg * SEG) * DH + dl * 8;
  float o[8] = {};
#pragma unroll
  for (int ss = 0; ss < 16; ss++) {
    int row = rh * 16 + ss;
    float p = probs[wave][gi * 33 + row];
    ushort8v vv = *(const ushort8v*)(vbase + (size_t)row * DH);
#pragma unroll
    for (int j = 0; j < 8; j++) o[j] += p * bf2f(vv[j]);
  }
#pragma unroll
  for (int off = 8; off < 64; off <<= 1) {
#pragma unroll
    for (int j = 0; j < 8; j++) o[j] += __shfl_xor(o[j], off, 64);
  }
  if (lane < 8) {
    ushort8v hi8, lo8;
#pragma unroll
    for (int j = 0; j < 8; j++) {
      unsigned short hb = f2bf(o[j]);
      hi8[j] = (short)hb;
      lo8[j] = (short)f2bf(o[j] - bf2f(hb));
    }
    *(ushort8v*)(ao2 + (size_t)n * 1024 + (h << 6) + (lane << 3)) = hi8;
    *(ushort8v*)(ao2 + (size_t)n * 1024 + 512 + (h << 6) + (lane << 3)) = lo8;
  }
}

// ---------------------------------------------------------------------------
extern "C" void kernel_launch(void* const* d_in, const int* in_sizes, int n_in,
                              void* d_out, int out_size, void* d_ws, size_t ws_size,
                              hipStream_t stream)
{
  const float* x      = (const float*)d_in[0];   // (1,2048,512)
  const float* w_qkv  = (const float*)d_in[1];   // (1536,512)
  const float* w_proj = (const float*)d_in[2];   // (512,512)
  const float* b_proj = (const float*)d_in[3];   // (512,)
  float* out = (float*)d_out;                    // (1,2048,512)

  float* base = (float*)d_ws;
  float* qbuf = base;                                        // 1,048,576 f
  // kbuf slot (base+1048576) now unused: centroid fused, fp32 K dead
  unsigned short* vbf = (unsigned short*)(base + 2097152);   // 8x2048x64 bf16
  unsigned short* kbf = (unsigned short*)(base + 2621440);   // 8x2048x64 bf16
  float* cent = base + 3145728;                              // 32,768 f
  int*   topk = (int*)(base + 3178496);                      // 65,536 i
  unsigned short* X2  = (unsigned short*)(base + 3244032);   // 2048x1024 bf16 (2-term)
  unsigned short* W2v = (unsigned short*)(base + 4292608);   // 512x1024  (V rows of w_qkv)
  unsigned short* WP2 = (unsigned short*)(base + 4554752);   // 512x1024  (w_proj)
  unsigned short* AO2 = X2;  // overlay: X2 dead after V GEMM

  // 1. fused 2-term bf16 splits (x, V-rows of w_qkv, w_proj)
  split3_kernel<<<6144, 256, 0, stream>>>(x, w_qkv + 1024 * 512, w_proj,
                                          X2, W2v, WP2);
  // 2. Q/K fp32 GEMM (R10 body, chain frozen) + bf16 K + fused exact centroid
  {
    dim3 grid(1024 / 64, N_TOK / 64);
    gemm_qk<<<grid, 256, 0, stream>>>(x, w_qkv, qbuf, kbf, cent);
  }
  // 3. V via bf16-split MFMA (swizzled LDS) -> single-bf16 vbf
  {
    dim3 grid(512 / 64, N_TOK / 64);
    gemm_mfma<<<grid, 256, 0, stream>>>(X2, W2v, vbf, nullptr, nullptr, 0, 0);
  }
  // 4. route + top-4 (bit-exact scores)
  route_topk_kernel<<<(H_NUM * N_TOK) / 4, 256, 0, stream>>>(qbuf, cent, topk);
  // 5. sparse attention (bf16 gather) -> 2-term AO2 (overlays X2)
  attn_kernel<<<(H_NUM * N_TOK) / 4, 256, 0, stream>>>(qbuf, kbf, vbf, topk, AO2);
  // 6. proj GEMM (MFMA swizzled, 3 products) + bias
  {
    dim3 grid(C_DIM / 64, N_TOK / 64);
    gemm_mfma<<<grid, 256, 0, stream>>>(AO2, WP2, nullptr, out, b_proj, C_DIM, 1);
  }
}

// Round 14
// 180.755 us; speedup vs baseline: 1.0929x; 1.0480x over previous
//
#include <hip/hip_runtime.h>
#include <hip/hip_bf16.h>
#include <math.h>

#define N_TOK 2048
#define C_DIM 512
#define H_NUM 8
#define DH 64
#define M_LM 64
#define SEG 32
#define KL 4
#define SCALE 0.125f

typedef __attribute__((ext_vector_type(8))) short short8;
typedef __attribute__((ext_vector_type(8))) unsigned short ushort8v;
typedef __attribute__((ext_vector_type(4))) float f32x4;

__device__ inline unsigned short f2bf(float f) {
  unsigned u = __float_as_uint(f);
  u += 0x7FFF + ((u >> 16) & 1);
  return (unsigned short)(u >> 16);
}
__device__ inline float bf2f(unsigned short h) {
  return __uint_as_float(((unsigned)h) << 16);
}

// LDS swizzle for the MFMA GEMM (R7-proven): k-octet stride 1024B is 0 mod 32
// banks; XOR row bits with ko, same on write and read => layout-only.
__device__ inline int swz(int ko, int row) {
  return ((ko * 64 + row) * 8) ^ (ko << 3);
}

// gemm_qk staging rotation (R10-proven: conflicts 3.15M -> 0).
__device__ inline int qrot(int k, int c) {
  return (c & ~3) | ((c + (k >> 3)) & 3);
}

// ---------------------------------------------------------------------------
// Q/K fp32 GEMM — R13 body (64x64, BK=32, rotation, fused bit-exact centroid
// in the K-role epilogue, no fp32 K store). CLOSED: R5/R6/R8/R9/R11/R12 all
// neutral-or-regressed; R13's fusion is the keeper (44 us, conflicts 0).
// ---------------------------------------------------------------------------
__global__ __launch_bounds__(256) void gemm_qk(
    const float* __restrict__ A, const float* __restrict__ B,
    float* __restrict__ out_q, unsigned short* __restrict__ kbf,
    float* __restrict__ cent)
{
  __shared__ float As[32][68];   // [k][m], pad->16B-aligned rows
  __shared__ float Bs[32][68];   // [k][j]
  int tid = threadIdx.x;
  int tx = tid & 15, ty = tid >> 4;
  int row0 = blockIdx.y << 6;
  int col0 = blockIdx.x << 6;
  float acc[4][4] = {};
  int kk = tid & 31, rr = tid >> 5;   // staging: 32 k-cols x 8 row-groups

  float pa[8], pb[8];
#pragma unroll
  for (int i = 0; i < 8; i++) {
    pa[i] = A[(size_t)(row0 + rr + i * 8) * 512 + kk];
    pb[i] = B[(size_t)(col0 + rr + i * 8) * 512 + kk];
  }

  for (int k0 = 0; k0 < 512; k0 += 32) {
    __syncthreads();
#pragma unroll
    for (int i = 0; i < 8; i++) {
      As[kk][qrot(kk, rr + i * 8)] = pa[i];
      Bs[kk][qrot(kk, rr + i * 8)] = pb[i];
    }
    __syncthreads();
    if (k0 + 32 < 512) {
#pragma unroll
      for (int i = 0; i < 8; i++) {
        pa[i] = A[(size_t)(row0 + rr + i * 8) * 512 + k0 + 32 + kk];
        pb[i] = B[(size_t)(col0 + rr + i * 8) * 512 + k0 + 32 + kk];
      }
    }
#pragma unroll
    for (int kk2 = 0; kk2 < 32; kk2++) {
      const int a2 = kk2 >> 3;
      float ar[4], br[4];
      *(float4*)ar = *(const float4*)&As[kk2][ty << 2];
      *(float4*)br = *(const float4*)&Bs[kk2][tx << 2];
      float a[4], b[4];
#pragma unroll
      for (int j = 0; j < 4; j++) {
        a[j] = ar[(j + a2) & 3];
        b[j] = br[(j + a2) & 3];
      }
#pragma unroll
      for (int i = 0; i < 4; i++)
#pragma unroll
        for (int j = 0; j < 4; j++) acc[i][j] += a[i] * b[j];
    }
  }

  int role = col0 >> 9;
  int h = (col0 >> 6) & 7;
  if (role == 0) {
#pragma unroll
    for (int i = 0; i < 4; i++) {
      int n = row0 + (ty << 2) + i;
#pragma unroll
      for (int j = 0; j < 4; j++) {
        int d = (tx << 2) + j;
        out_q[(size_t)((h << 11) + n) * DH + d] = acc[i][j];
      }
    }
  } else {
    // bf16 K store + exact-order fused centroid (reuses dead As/Bs).
    __syncthreads();   // all lanes done reading As/Bs from the main loop
#pragma unroll
    for (int i = 0; i < 4; i++) {
      int nl = (ty << 2) + i;          // local row 0..63
#pragma unroll
      for (int j = 0; j < 4; j++) {
        int d = (tx << 2) + j;
        float v = acc[i][j];
        kbf[(size_t)((h << 11) + row0 + nl) * DH + d] = f2bf(v);
        if (nl < 32) As[nl][d] = v; else Bs[nl - 32][d] = v;
      }
    }
    __syncthreads();
    if (tid < 128) {
      int m_loc = tid >> 6, d = tid & 63;
      float s = 0.f;
      if (m_loc == 0) {
#pragma unroll
        for (int ss = 0; ss < SEG; ss++) s += As[ss][d];   // ascending n
      } else {
#pragma unroll
        for (int ss = 0; ss < SEG; ss++) s += Bs[ss][d];   // ascending n
      }
      int m = (row0 >> 5) + m_loc;
      cent[(h << 12) + (m << 6) + d] = s * (1.0f / SEG);
    }
  }
}

// ---------------------------------------------------------------------------
// Fused 2-term bf16 splits for x (rows 2048), w_qkv V-rows (512), w_proj (512).
// (R2 version, byte-identical.)
// ---------------------------------------------------------------------------
__global__ void split3_kernel(const float* __restrict__ x, const float* __restrict__ wv,
                              const float* __restrict__ wp,
                              unsigned short* __restrict__ X2,
                              unsigned short* __restrict__ W2v,
                              unsigned short* __restrict__ WP2)
{
  int idx = blockIdx.x * 256 + threadIdx.x;   // 0 .. 1572863
  const float* src; unsigned short* dst; int li;
  if (idx < 1048576)      { src = x;  dst = X2;  li = idx; }
  else if (idx < 1310720) { src = wv; dst = W2v; li = idx - 1048576; }
  else                    { src = wp; dst = WP2; li = idx - 1310720; }
  int r = li >> 9, k = li & 511;
  float a = src[li];
  unsigned short h1 = f2bf(a);
  float r1 = a - bf2f(h1);
  dst[(size_t)(r << 10) + k] = h1;
  dst[(size_t)(r << 10) + 512 + k] = f2bf(r1);
}

// ---------------------------------------------------------------------------
// bf16-split MFMA GEMM, 3 products + LDS XOR swizzle (R7-proven).
// mode 0: V-scatter as SINGLE bf16 -> ov16[(h<<11)+row][d]
// mode 1: ofull = acc + bias (fp32).
// ---------------------------------------------------------------------------
__global__ __launch_bounds__(256) void gemm_mfma(
    const unsigned short* __restrict__ A2, const unsigned short* __restrict__ B2,
    unsigned short* __restrict__ ov16, float* __restrict__ ofull,
    const float* __restrict__ bias, int ldout, int mode)
{
  __shared__ short Al[4096];
  __shared__ short Bl[4096];
  int tid = threadIdx.x;
  int lane = tid & 63, w = tid >> 6;
  int row0 = blockIdx.y << 6, col0 = blockIdx.x << 6;
  int wr = (w >> 1) * 32, wc = (w & 1) * 32;
  int m_lo = tid & 7, h8 = (tid >> 3) & 7, m_hi = tid >> 6;
  int ms = m_hi * 8 + m_lo;  // 0..31
  int q = lane >> 4, ln = lane & 15;

  f32x4 acc[2][2];
#pragma unroll
  for (int mi = 0; mi < 2; mi++)
#pragma unroll
    for (int ni = 0; ni < 2; ni++)
#pragma unroll
      for (int r = 0; r < 4; r++) acc[mi][ni][r] = 0.0f;

  for (int s = 0; s < 24; s++) {
    int ka = (s < 8) ? s * 64 : (s < 16) ? 512 + (s - 8) * 64 : (s - 16) * 64;
    int kb = (s < 8) ? s * 64 : (s < 16) ? (s - 8) * 64 : 512 + (s - 16) * 64;
    short8 a0 = *(const short8*)(A2 + (size_t)(row0 + ms) * 1024 + ka + h8 * 8);
    short8 a1 = *(const short8*)(A2 + (size_t)(row0 + ms + 32) * 1024 + ka + h8 * 8);
    short8 b0 = *(const short8*)(B2 + (size_t)(col0 + ms) * 1024 + kb + h8 * 8);
    short8 b1 = *(const short8*)(B2 + (size_t)(col0 + ms + 32) * 1024 + kb + h8 * 8);
    __syncthreads();
    *(short8*)&Al[swz(h8, ms)] = a0;
    *(short8*)&Al[swz(h8, ms + 32)] = a1;
    *(short8*)&Bl[swz(h8, ms)] = b0;
    *(short8*)&Bl[swz(h8, ms + 32)] = b1;
    __syncthreads();
    short8 af[2][2], bf[2][2];
#pragma unroll
    for (int sub = 0; sub < 2; sub++)
#pragma unroll
      for (int i = 0; i < 2; i++) {
        af[sub][i] = *(const short8*)&Al[swz(sub * 4 + q, wr + i * 16 + ln)];
        bf[sub][i] = *(const short8*)&Bl[swz(sub * 4 + q, wc + i * 16 + ln)];
      }
#pragma unroll
    for (int sub = 0; sub < 2; sub++)
#pragma unroll
      for (int mi = 0; mi < 2; mi++)
#pragma unroll
        for (int ni = 0; ni < 2; ni++)
          acc[mi][ni] = __builtin_amdgcn_mfma_f32_16x16x32_bf16(
              af[sub][mi], bf[sub][ni], acc[mi][ni], 0, 0, 0);
  }

  if (mode == 0) {
    int hh = (col0 >> 6) & 7;
#pragma unroll
    for (int mi = 0; mi < 2; mi++)
#pragma unroll
      for (int ni = 0; ni < 2; ni++)
#pragma unroll
        for (int r = 0; r < 4; r++) {
          int row = row0 + wr + mi * 16 + q * 4 + r;
          int d = wc + ni * 16 + ln;
          ov16[(size_t)((hh << 11) + row) * DH + d] = f2bf(acc[mi][ni][r]);
        }
  } else {
#pragma unroll
    for (int mi = 0; mi < 2; mi++)
#pragma unroll
      for (int ni = 0; ni < 2; ni++)
#pragma unroll
        for (int r = 0; r < 4; r++) {
          int row = row0 + wr + mi * 16 + q * 4 + r;
          int col = col0 + wc + ni * 16 + ln;
          ofull[(size_t)row * ldout + col] = acc[mi][ni][r] + bias[col];
        }
  }
}

// ---------------------------------------------------------------------------
// FUSED route + top-4 + sparse attention (this round's single change).
// Route phase is byte-identical to the frozen route_topk_kernel: same centT
// staging, same dot order, same butterfly. Key observation: after the xor
// butterfly ALL lanes hold the final (max,id) — the old `if(lane==0)` global
// write was mere materialization. So segArr[r]=id stays in registers and the
// attn phase (byte-identical to R2's passing attn body) runs in the same
// wave. q is read once into qs[][] and the attn phase reads its fragments
// from there (same bits, 16B-aligned). topk global round-trip + one launch
// deleted; no arithmetic change anywhere => absmax must stay 0.00048828125.
// ---------------------------------------------------------------------------
__global__ __launch_bounds__(256) void route_attn_kernel(
    const float* __restrict__ qb, const float* __restrict__ cent,
    const unsigned short* __restrict__ kbf, const unsigned short* __restrict__ vbf,
    unsigned short* __restrict__ ao2)
{
  __shared__ float centT[64][65];
  __shared__ float qs[4][64];
  __shared__ float probs[4][132];   // [wave][si*33 + ss]
  int tid = threadIdx.x;
  int wave = tid >> 6, lane = tid & 63;
  int qi = (blockIdx.x << 2) + wave;
  int h = qi >> 11, n = qi & 2047;   // h uniform across block (2048 % 4 == 0)

  // ---- route phase (frozen math) ----
  qs[wave][lane] = qb[(size_t)qi * DH + lane];
  const float4* c4 = (const float4*)(cent + ((size_t)h << 12));
#pragma unroll
  for (int i = 0; i < 4; i++) {
    int f4 = tid + 256 * i;       // 0..1023
    int m = f4 >> 4;
    int d0 = (f4 & 15) * 4;
    float4 v = c4[f4];
    centT[d0][m] = v.x; centT[d0 + 1][m] = v.y;
    centT[d0 + 2][m] = v.z; centT[d0 + 3][m] = v.w;
  }
  __syncthreads();
  float dot = 0.f;
#pragma unroll
  for (int d = 0; d < 64; d++) dot += qs[wave][d] * centT[d][lane];
  float val = dot * SCALE;
  int segArr[4];
  for (int r = 0; r < KL; r++) {
    float v = val;
    int id = lane;
#pragma unroll
    for (int off = 32; off; off >>= 1) {
      float ov = __shfl_xor(v, off, 64);
      int oi = __shfl_xor(id, off, 64);
      if (ov > v || (ov == v && oi < id)) { v = ov; id = oi; }
    }
    segArr[r] = id;                  // all lanes converged to the same id
    if (lane == id) val = -INFINITY;
  }

  // ---- attn phase (frozen math; q fragments from qs, same bits) ----
  const float* qrow = &qs[wave][0];
  float4 qreg[4];
#pragma unroll
  for (int j = 0; j < 2; j++) {
    qreg[j * 2]     = *(const float4*)(qrow + ((lane & 3) + 4 * j) * 8);
    qreg[j * 2 + 1] = *(const float4*)(qrow + ((lane & 3) + 4 * j) * 8 + 4);
  }

  float e[8];
  float score[8];
#pragma unroll
  for (int g = 0; g < 8; g++) {
    int seg = segArr[g >> 1];
    int key_n = seg * SEG + (lane >> 2) + 16 * (g & 1);
    const unsigned short* krow = kbf + ((size_t)(h << 11) + key_n) * DH;
    float a0 = 0.f, a1 = 0.f, a2 = 0.f, a3 = 0.f;
#pragma unroll
    for (int j = 0; j < 2; j++) {
      ushort8v kv = *(const ushort8v*)(krow + ((lane & 3) + 4 * j) * 8);
      float4 q0 = qreg[j * 2], q1 = qreg[j * 2 + 1];
      a0 += q0.x * bf2f(kv[0]); a1 += q0.y * bf2f(kv[1]);
      a2 += q0.z * bf2f(kv[2]); a3 += q0.w * bf2f(kv[3]);
      a0 += q1.x * bf2f(kv[4]); a1 += q1.y * bf2f(kv[5]);
      a2 += q1.z * bf2f(kv[6]); a3 += q1.w * bf2f(kv[7]);
    }
    float acc = (a0 + a1) + (a2 + a3);
    acc += __shfl_xor(acc, 1, 64);
    acc += __shfl_xor(acc, 2, 64);
    score[g] = acc * SCALE;
  }
  float mx = score[0];
#pragma unroll
  for (int g = 1; g < 8; g++) mx = fmaxf(mx, score[g]);
#pragma unroll
  for (int off = 4; off < 64; off <<= 1) mx = fmaxf(mx, __shfl_xor(mx, off, 64));
  float ls = 0.f;
#pragma unroll
  for (int g = 0; g < 8; g++) { e[g] = expf(score[g] - mx); ls += e[g]; }
#pragma unroll
  for (int off = 4; off < 64; off <<= 1) ls += __shfl_xor(ls, off, 64);
  float inv = 1.0f / ls;
  if ((lane & 3) == 0) {
#pragma unroll
    for (int g = 0; g < 8; g++)
      probs[wave][(g >> 1) * 33 + (lane >> 2) + 16 * (g & 1)] = e[g] * inv;
  }
  __syncthreads();

  // PV
  int gi = lane >> 4, lx = lane & 15;
  int rh = lx >> 3, dl = lx & 7;
  int seg = segArr[gi];
  const unsigned short* vbase = vbf + ((size_t)(h << 11) + seg * SEG) * DH + dl * 8;
  float o[8] = {};
#pragma unroll
  for (int ss = 0; ss < 16; ss++) {
    int row = rh * 16 + ss;
    float p = probs[wave][gi * 33 + row];
    ushort8v vv = *(const ushort8v*)(vbase + (size_t)row * DH);
#pragma unroll
    for (int j = 0; j < 8; j++) o[j] += p * bf2f(vv[j]);
  }
#pragma unroll
  for (int off = 8; off < 64; off <<= 1) {
#pragma unroll
    for (int j = 0; j < 8; j++) o[j] += __shfl_xor(o[j], off, 64);
  }
  if (lane < 8) {
    ushort8v hi8, lo8;
#pragma unroll
    for (int j = 0; j < 8; j++) {
      unsigned short hb = f2bf(o[j]);
      hi8[j] = (short)hb;
      lo8[j] = (short)f2bf(o[j] - bf2f(hb));
    }
    *(ushort8v*)(ao2 + (size_t)n * 1024 + (h << 6) + (lane << 3)) = hi8;
    *(ushort8v*)(ao2 + (size_t)n * 1024 + 512 + (h << 6) + (lane << 3)) = lo8;
  }
}

// ---------------------------------------------------------------------------
extern "C" void kernel_launch(void* const* d_in, const int* in_sizes, int n_in,
                              void* d_out, int out_size, void* d_ws, size_t ws_size,
                              hipStream_t stream)
{
  const float* x      = (const float*)d_in[0];   // (1,2048,512)
  const float* w_qkv  = (const float*)d_in[1];   // (1536,512)
  const float* w_proj = (const float*)d_in[2];   // (512,512)
  const float* b_proj = (const float*)d_in[3];   // (512,)
  float* out = (float*)d_out;                    // (1,2048,512)

  float* base = (float*)d_ws;
  float* qbuf = base;                                        // 1,048,576 f
  // base+1048576 slot free (fp32 K dead since R13)
  unsigned short* vbf = (unsigned short*)(base + 2097152);   // 8x2048x64 bf16
  unsigned short* kbf = (unsigned short*)(base + 2621440);   // 8x2048x64 bf16
  float* cent = base + 3145728;                              // 32,768 f
  // topk slot (base+3178496) free since R14 fusion
  unsigned short* X2  = (unsigned short*)(base + 3244032);   // 2048x1024 bf16 (2-term)
  unsigned short* W2v = (unsigned short*)(base + 4292608);   // 512x1024  (V rows of w_qkv)
  unsigned short* WP2 = (unsigned short*)(base + 4554752);   // 512x1024  (w_proj)
  unsigned short* AO2 = X2;  // overlay: X2 dead after V GEMM

  // 1. fused 2-term bf16 splits (x, V-rows of w_qkv, w_proj)
  split3_kernel<<<6144, 256, 0, stream>>>(x, w_qkv + 1024 * 512, w_proj,
                                          X2, W2v, WP2);
  // 2. Q/K fp32 GEMM (R13 body, chain frozen) + bf16 K + fused exact centroid
  {
    dim3 grid(1024 / 64, N_TOK / 64);
    gemm_qk<<<grid, 256, 0, stream>>>(x, w_qkv, qbuf, kbf, cent);
  }
  // 3. V via bf16-split MFMA (swizzled LDS) -> single-bf16 vbf
  {
    dim3 grid(512 / 64, N_TOK / 64);
    gemm_mfma<<<grid, 256, 0, stream>>>(X2, W2v, vbf, nullptr, nullptr, 0, 0);
  }
  // 4. fused route + top-4 + sparse attention -> 2-term AO2 (overlays X2)
  route_attn_kernel<<<(H_NUM * N_TOK) / 4, 256, 0, stream>>>(qbuf, cent, kbf,
                                                             vbf, AO2);
  // 5. proj GEMM (MFMA swizzled, 3 products) + bias
  {
    dim3 grid(C_DIM / 64, N_TOK / 64);
    gemm_mfma<<<grid, 256, 0, stream>>>(AO2, WP2, nullptr, out, b_proj, C_DIM, 1);
  }
}